// Round 8
// baseline (127.483 us; speedup 1.0000x reference)
//
#include <hip/hip_runtime.h>
#include <math.h>

#define NN 320      // particles
#define DD 64       // dim
#define NPERM 1001  // identity + 1000 permutations
#define KPB 4       // perms per qf block
#define NBLK ((NPERM + KPB - 1) / KPB)   // 251 blocks = 1 per CU
#define NW 10                            // u32 words per 320-bit mask
#define PROWS 16                         // rows per LDS panel
#define NPANEL (NN / PROWS)              // 20 panels
#define PANEL_F4 (PROWS * NN * 2 / 4)    // 2560 float4 per panel
#define NPAIRF ((double)(NN * (NN - 1) / 2))   // 51040

// ---------------------------------------------------------------------------
// Math (u in {+-1} since Fv=-1, Bv=+1; PASSING rounds 1,2,3,5,6,7 absmax 0):
//   d_ab = da_ab + (u_a*u_b)*dh_ab,  da=(dp+dm)/2, dh=(dp-dm)/2
//   SV_ordered = C0 + u^T Dh u - 2 q^T Da q - 2 (qu)^T Dh (qu), C0 = Sum da
//     (diagonal cancels exactly in this combination)
//   SV2 = N*S - |y|^2,  y = Sum_a u_a x_a
// Round-7 post-mortem: qf ~34us vs ~5us VALU floor — latency-exposed at
// 2 waves/SIMD with 1-deep register prefetch (L2 ~300cy > 220cy cover).
// This round: DAH streamed through LDS in 16-row double-buffered panels.
// Per iter: {ds_write p+1 | issue loads p+2 | compute p from LDS | barrier}.
// Loads get a full compute phase to land (T14); compute reads are ds_read_b64
// at the wave64 floor. 64 strips x 8 rowoffs (512 active, col cache 60 VGPR).
// launch_bounds(512) plain — min-waves>=4 poison (2x confirmed) avoided.
// ws: srow@0 (320 f64) | rsda@4096 (320 f64) | DAH@1048576 (800KB)
// ---------------------------------------------------------------------------

// Gram row; DAH = {da,dh}; per-row srow/rsda partials (no atomics).
__global__ __launch_bounds__(NN) void dah_kernel(const float* __restrict__ data,
                                                 float2* __restrict__ DAH,
                                                 double* __restrict__ srow,
                                                 double* __restrict__ rsda) {
    __shared__ float rowa[DD];
    __shared__ double cr[5];
    const int a = blockIdx.x;
    const int t = threadIdx.x;
    if (t < DD) rowa[t] = data[a * DD + t];
    __syncthreads();
    const float* rb = data + t * DD;
    float g = 0.f, sa = 0.f, st = 0.f;
#pragma unroll
    for (int k = 0; k < DD; k += 4) {
        const float4 x = *(const float4*)(rb + k);
        const float r0 = rowa[k], r1 = rowa[k + 1], r2 = rowa[k + 2], r3 = rowa[k + 3];
        g  = fmaf(r0, x.x, g);   g  = fmaf(r1, x.y, g);
        g  = fmaf(r2, x.z, g);   g  = fmaf(r3, x.w, g);
        sa = fmaf(r0, r0, sa);   sa = fmaf(r1, r1, sa);
        sa = fmaf(r2, r2, sa);   sa = fmaf(r3, r3, sa);
        st = fmaf(x.x, x.x, st); st = fmaf(x.y, x.y, st);
        st = fmaf(x.z, x.z, st); st = fmaf(x.w, x.w, st);
    }
    const float sum = sa + st;
    const float dp = sqrtf(fmaxf(fmaf(-2.f, g, sum), 0.f));
    const float dm = sqrtf(fmaxf(fmaf( 2.f, g, sum), 0.f));
    const float da = 0.5f * (dp + dm);
    const float dh = 0.5f * (dp - dm);
    DAH[(size_t)a * NN + t] = make_float2(da, dh);

    double cd = (double)da;
    for (int off = 32; off; off >>= 1) cd += __shfl_down(cd, off, 64);
    const int wid = t >> 6, lane = t & 63;
    if (lane == 0) cr[wid] = cd;
    __syncthreads();
    if (t == 0) {
        double tot = 0.0;
#pragma unroll
        for (int i = 0; i < 5; ++i) tot += cr[i];
        rsda[a] = tot;                 // row-sum of da
        srow[a] = (double)sa;          // |x_a|^2
    }
}

// One block = 4 perms, all 320 rows via 20 LDS-staged 16-row panels.
// 512 thr = 64 col-strips (5 strided cols each) x 8 rowoffs (wave = rowoff).
__global__ __launch_bounds__(512) void qf_kernel(const float* __restrict__ data,
                                                 const int* __restrict__ types,
                                                 const int* __restrict__ perms,
                                                 const float* __restrict__ fermp,
                                                 const float* __restrict__ bosp,
                                                 const float* __restrict__ DAHf,
                                                 const double* __restrict__ srow,
                                                 const double* __restrict__ rsda,
                                                 float* __restrict__ out) {
    __shared__ float buf[2][PROWS * NN * 2];           // 2 x 40 KB panels
    __shared__ unsigned cb[KPB][2 * NW];
    __shared__ __align__(16) float rcoef[NN * 20];     // [r][k pad5] {u,q,v,0}
    __shared__ float ysh[KPB][2][DD];
    __shared__ double red[8][12];
    __shared__ double redS[8], redC[8], scal[KPB];

    const int pg = blockIdx.x;
    const int t  = threadIdx.x;
    const int strip  = t & 63;
    const int rowoff = t >> 6;

    // ---- inline coefficient decode (bits in LDS) ----
    if (t < KPB * 2 * NW) ((unsigned*)cb)[t] = 0u;
    __syncthreads();
    const float Fv = *fermp, Bv = *bosp;
    if (t < NN) {
        const int i  = t;
        const int ti = types[i];
#pragma unroll
        for (int k = 0; k < KPB; ++k) {
            int p = pg * KPB + k; if (p >= NPERM) p = NPERM - 1;
            const int a  = (p == 0) ? i : perms[(size_t)(p - 1) * NN + i];
            const int ta = types[a];
            float u = 1.f;
            if (a != i) u = (ti == 0 && ta == 0) ? Fv : ((ti == 1 && ta == 1) ? Bv : 1.f);
            if (u < 0.f) atomicOr(&cb[k][a >> 5], 1u << (a & 31));
            if (ti == 0) atomicOr(&cb[k][NW + (a >> 5)], 1u << (a & 31));
        }
    }
    __syncthreads();

    // ---- panel 0 loads issued first (latency overlaps the decode below) ----
    const float4* dall = (const float4*)DAHf;
    float4 stg[5];
#pragma unroll
    for (int j = 0; j < 5; ++j) stg[j] = dall[t + 512 * j];

    // Row coefficients, stride 5 float4 = 80 B (broadcast reads, no conflict).
    for (int j = t; j < NN * KPB; j += 512) {
        const int r = j >> 2, k = j & 3;
        const unsigned ubit = (cb[k][r >> 5]        >> (r & 31)) & 1u;
        const unsigned qbit = (cb[k][NW + (r >> 5)] >> (r & 31)) & 1u;
        const float u = ubit ? -1.f : 1.f;
        *(float4*)&rcoef[(r * 5 + k) * 4] =
            make_float4(u, qbit ? 1.f : 0.f, qbit ? u : 0.f, 0.f);
    }

    // Column cache: 5 strided cols (c = strip + 64e) x 3 coefs x 4 perms.
    float ub[KPB][5], qb[KPB][5], vb[KPB][5];
#pragma unroll
    for (int k = 0; k < KPB; ++k) {
#pragma unroll
        for (int e = 0; e < 5; ++e) {
            const int w = (strip >> 5) + 2 * e, b = strip & 31;
            const float u = ((cb[k][w] >> b) & 1u) ? -1.f : 1.f;
            const bool  q = ((cb[k][NW + w] >> b) & 1u) != 0u;
            ub[k][e] = u;
            qb[k][e] = q ? 1.f : 0.f;
            vb[k][e] = q ? u : 0.f;
        }
    }

    // Prologue: write panel 0, issue panel 1, one barrier.
    {
        float4* db = (float4*)buf[0];
#pragma unroll
        for (int j = 0; j < 5; ++j) db[t + 512 * j] = stg[j];
#pragma unroll
        for (int j = 0; j < 5; ++j) stg[j] = dall[PANEL_F4 + t + 512 * j];
    }
    __syncthreads();

    // ---- main sweep ----
    float A2[KPB] = {0.f, 0.f, 0.f, 0.f};   // u^T Dh u
    float A3[KPB] = {0.f, 0.f, 0.f, 0.f};   // q^T Da q
    float A4[KPB] = {0.f, 0.f, 0.f, 0.f};   // (qu)^T Dh (qu)

    auto row_compute = [&](const float* rowp, const float* ap) {
        const float2 m0 = *(const float2*)(rowp + 2 * strip);
        const float2 m1 = *(const float2*)(rowp + 2 * strip + 128);
        const float2 m2 = *(const float2*)(rowp + 2 * strip + 256);
        const float2 m3 = *(const float2*)(rowp + 2 * strip + 384);
        const float2 m4 = *(const float2*)(rowp + 2 * strip + 512);
#pragma unroll
        for (int k = 0; k < KPB; ++k) {
            const float4 rp = *(const float4*)(ap + 4 * k);  // {u_a, q_a, v_a}
            float r2 = ub[k][0] * m0.y;
            float r3 = qb[k][0] * m0.x;
            float r4 = vb[k][0] * m0.y;
            r2 = fmaf(ub[k][1], m1.y, r2); r3 = fmaf(qb[k][1], m1.x, r3); r4 = fmaf(vb[k][1], m1.y, r4);
            r2 = fmaf(ub[k][2], m2.y, r2); r3 = fmaf(qb[k][2], m2.x, r3); r4 = fmaf(vb[k][2], m2.y, r4);
            r2 = fmaf(ub[k][3], m3.y, r2); r3 = fmaf(qb[k][3], m3.x, r3); r4 = fmaf(vb[k][3], m3.y, r4);
            r2 = fmaf(ub[k][4], m4.y, r2); r3 = fmaf(qb[k][4], m4.x, r3); r4 = fmaf(vb[k][4], m4.y, r4);
            A2[k] = fmaf(rp.x, r2, A2[k]);
            A3[k] = fmaf(rp.y, r3, A3[k]);
            A4[k] = fmaf(rp.z, r4, A4[k]);
        }
    };

    for (int p = 0; p < NPANEL; ++p) {
        if (p + 1 < NPANEL) {            // write panel p+1 (regs loaded last iter)
            float4* db = (float4*)buf[(p + 1) & 1];
#pragma unroll
            for (int j = 0; j < 5; ++j) db[t + 512 * j] = stg[j];
        }
        if (p + 2 < NPANEL) {            // issue loads for panel p+2 (lands under compute)
#pragma unroll
            for (int j = 0; j < 5; ++j)
                stg[j] = dall[(size_t)(p + 2) * PANEL_F4 + t + 512 * j];
        }
        const float* B = buf[p & 1];
        row_compute(B + rowoff * (2 * NN),
                    rcoef + (p * PROWS + rowoff) * 20);
        row_compute(B + (rowoff + 8) * (2 * NN),
                    rcoef + (p * PROWS + rowoff + 8) * 20);
        if (p + 1 < NPANEL) __syncthreads();
    }

    // ---- y partials: 4 perms x 2 row-halves x 64 dims ----
    {
        const int k = t >> 7, sub = t & 127;
        const int j = sub >> 6, d = sub & 63;
        float acc = 0.f;
        const int r0 = j * (NN / 2);
        for (int r = r0; r < r0 + NN / 2; ++r)
            acc = fmaf(rcoef[(r * 5 + k) * 4], data[(size_t)r * DD + d], acc);
        ysh[k][j][d] = acc;
    }

    // ---- A partials: f32 -> f64 -> wave -> cross-wave LDS ----
    double rd[12];
#pragma unroll
    for (int k = 0; k < KPB; ++k) {
        rd[k]     = (double)A2[k];
        rd[4 + k] = (double)A3[k];
        rd[8 + k] = (double)A4[k];
    }
    for (int off = 32; off; off >>= 1) {
#pragma unroll
        for (int j = 0; j < 12; ++j) rd[j] += __shfl_down(rd[j], off, 64);
    }
    const int wid = t >> 6, lane = t & 63;
    if (lane == 0) {
#pragma unroll
        for (int j = 0; j < 12; ++j) red[wid][j] = rd[j];
    }

    // ---- S and C0 (320-wide f64 reduce) ----
    {
        double sS = 0.0, sC = 0.0;
        if (t < NN) { sS = srow[t]; sC = rsda[t]; }
        for (int off = 32; off; off >>= 1) {
            sS += __shfl_down(sS, off, 64);
            sC += __shfl_down(sC, off, 64);
        }
        if (lane == 0) { redS[wid] = sS; redC[wid] = sC; }
    }
    __syncthreads();

    // ---- |y|^2: wave k reduces dim axis for perm k ----
    if (t < KPB * 64) {
        const int k = t >> 6, d = t & 63;
        const float yv = ysh[k][0][d] + ysh[k][1][d];
        double yy = (double)yv * (double)yv;
        for (int off = 32; off; off >>= 1) yy += __shfl_down(yy, off, 64);
        if ((t & 63) == 0) scal[k] = yy;
    }
    __syncthreads();

    if (t == 0) {
        double S = 0.0, C0 = 0.0;
#pragma unroll
        for (int w = 0; w < 8; ++w) { S += redS[w]; C0 += redC[w]; }
#pragma unroll
        for (int k = 0; k < KPB; ++k) {
            const int p = pg * KPB + k;
            if (p < NPERM) {
                double T2 = 0.0, T3 = 0.0, T4 = 0.0;
#pragma unroll
                for (int w = 0; w < 8; ++w) {
                    T2 += red[w][k];
                    T3 += red[w][4 + k];
                    T4 += red[w][8 + k];
                }
                const double SV  = 0.5 * (C0 + T2 - 2.0 * T3 - 2.0 * T4);
                const double SV2 = (double)NN * S - scal[k];
                out[p] = (float)((SV2 - SV * SV / NPAIRF) / (NPAIRF - 1.0));
            }
        }
    }
}

extern "C" void kernel_launch(void* const* d_in, const int* in_sizes, int n_in,
                              void* d_out, int out_size, void* d_ws, size_t ws_size,
                              hipStream_t stream) {
    const float* data  = (const float*)d_in[0];
    const float* fermp = (const float*)d_in[1];
    const float* bosp  = (const float*)d_in[2];
    const int*   types = (const int*)d_in[3];
    const int*   perms = (const int*)d_in[4];
    float* out = (float*)d_out;

    double* srow = (double*)d_ws;                       // 320 f64
    double* rsda = (double*)((char*)d_ws + 4096);       // 320 f64
    float2* DAH  = (float2*)((char*)d_ws + 1048576);    // 320*320 float2 = 800 KB

    dah_kernel<<<NN, NN, 0, stream>>>(data, DAH, srow, rsda);
    qf_kernel<<<NBLK, 512, 0, stream>>>(data, types, perms, fermp, bosp,
                                        (const float*)DAH, srow, rsda, out);
}

// Round 9
// 98.409 us; speedup vs baseline: 1.2954x; 1.2954x over previous
//
#include <hip/hip_runtime.h>
#include <math.h>

#define NN 320      // particles
#define DD 64       // dim
#define ROWF (NN * 2)                    // floats per DAH row (da,dh interleaved)
#define NPERM 1001  // identity + 1000 permutations
#define KPB 4       // perms per qf block
#define NBLK ((NPERM + KPB - 1) / KPB)   // 251 blocks = 1 per CU
#define NW 10                            // u32 words per 320-bit mask
#define NITER 20                         // 20 iters x 16 rowoffs = 320 rows
#define NPAIRF ((double)(NN * (NN - 1) / 2))   // 51040

// ---------------------------------------------------------------------------
// Math (u in {+-1} since Fv=-1, Bv=+1; PASSING rounds 1,2,3,5,6,7,8 absmax 0):
//   d_ab = da_ab + (u_a*u_b)*dh_ab,  da=(dp+dm)/2, dh=(dp-dm)/2
//   SV_ordered = C0 + u^T Dh u - 2 q^T Da q - 2 (qu)^T Dh (qu), C0 = Sum da
//   SV2 = N*S - |y|^2,  y = Sum_a u_a x_a
// Round-8 post-mortem: LDS staging ADDED 20us (148KB LDS, panel barriers);
// stall is occupancy (8 waves/CU in ALL prior variants, VALUBusy 16-20%),
// not L2 BW (FETCH 4.3MB). This round: ONE 1024-thread block per CU -> 16
// waves/CU BY CONSTRUCTION (resident for any VGPR <= 512; immune to the
// VGPR-lottery failures of rounds 3/6). 64 strips x 16 rowoffs x 20 iters,
// no idle lanes, no tail. 5 coalesced float2 loads/lane/iter (512 B/wave
// chunks), 1-deep prefetch, col cache 60 VGPR (round-8-proven lean).
// ws: srow@0 (320 f64) | rsda@4096 (320 f64) | DAH@1048576 (800KB)
// ---------------------------------------------------------------------------

// Gram row; DAH = {da,dh}; per-row srow/rsda partials (no atomics).
__global__ __launch_bounds__(NN) void dah_kernel(const float* __restrict__ data,
                                                 float2* __restrict__ DAH,
                                                 double* __restrict__ srow,
                                                 double* __restrict__ rsda) {
    __shared__ float rowa[DD];
    __shared__ double cr[5];
    const int a = blockIdx.x;
    const int t = threadIdx.x;
    if (t < DD) rowa[t] = data[a * DD + t];
    __syncthreads();
    const float* rb = data + t * DD;
    float g = 0.f, sa = 0.f, st = 0.f;
#pragma unroll
    for (int k = 0; k < DD; k += 4) {
        const float4 x = *(const float4*)(rb + k);
        const float r0 = rowa[k], r1 = rowa[k + 1], r2 = rowa[k + 2], r3 = rowa[k + 3];
        g  = fmaf(r0, x.x, g);   g  = fmaf(r1, x.y, g);
        g  = fmaf(r2, x.z, g);   g  = fmaf(r3, x.w, g);
        sa = fmaf(r0, r0, sa);   sa = fmaf(r1, r1, sa);
        sa = fmaf(r2, r2, sa);   sa = fmaf(r3, r3, sa);
        st = fmaf(x.x, x.x, st); st = fmaf(x.y, x.y, st);
        st = fmaf(x.z, x.z, st); st = fmaf(x.w, x.w, st);
    }
    const float sum = sa + st;
    const float dp = sqrtf(fmaxf(fmaf(-2.f, g, sum), 0.f));
    const float dm = sqrtf(fmaxf(fmaf( 2.f, g, sum), 0.f));
    const float da = 0.5f * (dp + dm);
    const float dh = 0.5f * (dp - dm);
    DAH[(size_t)a * NN + t] = make_float2(da, dh);

    double cd = (double)da;
    for (int off = 32; off; off >>= 1) cd += __shfl_down(cd, off, 64);
    const int wid = t >> 6, lane = t & 63;
    if (lane == 0) cr[wid] = cd;
    __syncthreads();
    if (t == 0) {
        double tot = 0.0;
#pragma unroll
        for (int i = 0; i < 5; ++i) tot += cr[i];
        rsda[a] = tot;                 // row-sum of da
        srow[a] = (double)sa;          // |x_a|^2
    }
}

// One 1024-thread block = 4 perms, all 320 rows. 64 strips x 16 rowoffs.
// Per lane/iter: 5 coalesced float2 (cols strip+64e) + 4 LDS broadcast +
// ~72 fma. 16 waves/CU guaranteed by block size. Self-contained epilogue.
__global__ __launch_bounds__(1024) void qf_kernel(const float* __restrict__ data,
                                                  const int* __restrict__ types,
                                                  const int* __restrict__ perms,
                                                  const float* __restrict__ fermp,
                                                  const float* __restrict__ bosp,
                                                  const float* __restrict__ DAHf,
                                                  const double* __restrict__ srow,
                                                  const double* __restrict__ rsda,
                                                  float* __restrict__ out) {
    __shared__ unsigned cb[KPB][2 * NW];
    __shared__ __align__(16) float rcoef[NN * 20];     // [r][k pad5] {u,q,v,0} 25.6KB
    __shared__ float ysh[KPB][4][DD];
    __shared__ double red[16][12];
    __shared__ double redS[16], redC[16], scal[KPB];

    const int pg = blockIdx.x;
    const int t  = threadIdx.x;
    const int strip  = t & 63;        // column strip: cols strip + 64e, e=0..4
    const int rowoff = t >> 6;        // 0..15 (= wave id; wave-uniform)

    // ---- issue row-0 DAH loads first (latency hides under decode) ----
    const float* gp = DAHf + (size_t)rowoff * ROWF + 2 * strip;
    float2 m0 = *(const float2*)(gp);
    float2 m1 = *(const float2*)(gp + 128);
    float2 m2 = *(const float2*)(gp + 256);
    float2 m3 = *(const float2*)(gp + 384);
    float2 m4 = *(const float2*)(gp + 512);

    // ---- inline coefficient decode (bits in LDS) ----
    if (t < KPB * 2 * NW) ((unsigned*)cb)[t] = 0u;
    __syncthreads();
    const float Fv = *fermp, Bv = *bosp;
    if (t < NN) {
        const int i  = t;
        const int ti = types[i];
#pragma unroll
        for (int k = 0; k < KPB; ++k) {
            int p = pg * KPB + k; if (p >= NPERM) p = NPERM - 1;
            const int a  = (p == 0) ? i : perms[(size_t)(p - 1) * NN + i];
            const int ta = types[a];
            float u = 1.f;
            if (a != i) u = (ti == 0 && ta == 0) ? Fv : ((ti == 1 && ta == 1) ? Bv : 1.f);
            if (u < 0.f) atomicOr(&cb[k][a >> 5], 1u << (a & 31));
            if (ti == 0) atomicOr(&cb[k][NW + (a >> 5)], 1u << (a & 31));
        }
    }
    __syncthreads();

    // Row coefficients, stride 5 float4 = 80 B (wave-uniform broadcast reads).
    for (int j = t; j < NN * KPB; j += 1024) {
        const int r = j >> 2, k = j & 3;
        const unsigned ubit = (cb[k][r >> 5]        >> (r & 31)) & 1u;
        const unsigned qbit = (cb[k][NW + (r >> 5)] >> (r & 31)) & 1u;
        const float u = ubit ? -1.f : 1.f;
        *(float4*)&rcoef[(r * 5 + k) * 4] =
            make_float4(u, qbit ? 1.f : 0.f, qbit ? u : 0.f, 0.f);
    }

    // Column cache: 5 strided cols x 3 coefs x 4 perms = 60 VGPR.
    float ub[KPB][5], qb[KPB][5], vb[KPB][5];
#pragma unroll
    for (int k = 0; k < KPB; ++k) {
#pragma unroll
        for (int e = 0; e < 5; ++e) {
            const int w = (strip >> 5) + 2 * e, b = strip & 31;
            const float u = ((cb[k][w] >> b) & 1u) ? -1.f : 1.f;
            const bool  q = ((cb[k][NW + w] >> b) & 1u) != 0u;
            ub[k][e] = u;
            qb[k][e] = q ? 1.f : 0.f;
            vb[k][e] = q ? u : 0.f;
        }
    }
    __syncthreads();

    // ---- main sweep: 20 iters x 16 rowoffs = all 320 rows ----
    float A2[KPB] = {0.f, 0.f, 0.f, 0.f};   // u^T Dh u
    float A3[KPB] = {0.f, 0.f, 0.f, 0.f};   // q^T Da q
    float A4[KPB] = {0.f, 0.f, 0.f, 0.f};   // (qu)^T Dh (qu)

    auto row_compute = [&](const float* ap) {
#pragma unroll
        for (int k = 0; k < KPB; ++k) {
            const float4 rp = *(const float4*)(ap + 4 * k);  // {u_a, q_a, v_a}
            float r2 = ub[k][0] * m0.y;
            float r3 = qb[k][0] * m0.x;
            float r4 = vb[k][0] * m0.y;
            r2 = fmaf(ub[k][1], m1.y, r2); r3 = fmaf(qb[k][1], m1.x, r3); r4 = fmaf(vb[k][1], m1.y, r4);
            r2 = fmaf(ub[k][2], m2.y, r2); r3 = fmaf(qb[k][2], m2.x, r3); r4 = fmaf(vb[k][2], m2.y, r4);
            r2 = fmaf(ub[k][3], m3.y, r2); r3 = fmaf(qb[k][3], m3.x, r3); r4 = fmaf(vb[k][3], m3.y, r4);
            r2 = fmaf(ub[k][4], m4.y, r2); r3 = fmaf(qb[k][4], m4.x, r3); r4 = fmaf(vb[k][4], m4.y, r4);
            A2[k] = fmaf(rp.x, r2, A2[k]);
            A3[k] = fmaf(rp.y, r3, A3[k]);
            A4[k] = fmaf(rp.z, r4, A4[k]);
        }
    };

    for (int it = 0; it < NITER; ++it) {
        const float* gq = (it < NITER - 1) ? (gp + 16 * ROWF) : gp;  // next row
        const float2 n0 = *(const float2*)(gq);
        const float2 n1 = *(const float2*)(gq + 128);
        const float2 n2 = *(const float2*)(gq + 256);
        const float2 n3 = *(const float2*)(gq + 384);
        const float2 n4 = *(const float2*)(gq + 512);
        row_compute(rcoef + (it * 16 + rowoff) * 20);
        m0 = n0; m1 = n1; m2 = n2; m3 = n3; m4 = n4;
        gp = gq;
    }

    // ---- y partials: 4 perms x 4 row-groups x 64 dims = 1024 threads ----
    {
        const int k = t >> 8, sub = t & 255;
        const int j = sub >> 6, d = sub & 63;
        float acc = 0.f;
        for (int r = j * 80; r < j * 80 + 80; ++r)
            acc = fmaf(rcoef[(r * 5 + k) * 4], data[(size_t)r * DD + d], acc);
        ysh[k][j][d] = acc;
    }

    // ---- A partials: f32 -> f64 -> wave -> cross-wave LDS ----
    double rd[12];
#pragma unroll
    for (int k = 0; k < KPB; ++k) {
        rd[k]     = (double)A2[k];
        rd[4 + k] = (double)A3[k];
        rd[8 + k] = (double)A4[k];
    }
    for (int off = 32; off; off >>= 1) {
#pragma unroll
        for (int j = 0; j < 12; ++j) rd[j] += __shfl_down(rd[j], off, 64);
    }
    const int wid = t >> 6, lane = t & 63;
    if (lane == 0) {
#pragma unroll
        for (int j = 0; j < 12; ++j) red[wid][j] = rd[j];
    }

    // ---- S and C0 (320-wide f64 reduce; waves with t>=NN contribute 0) ----
    {
        double sS = 0.0, sC = 0.0;
        if (t < NN) { sS = srow[t]; sC = rsda[t]; }
        for (int off = 32; off; off >>= 1) {
            sS += __shfl_down(sS, off, 64);
            sC += __shfl_down(sC, off, 64);
        }
        if (lane == 0) { redS[wid] = sS; redC[wid] = sC; }
    }
    __syncthreads();

    // ---- |y|^2: wave k reduces dim axis for perm k ----
    if (t < KPB * 64) {
        const int k = t >> 6, d = t & 63;
        const float yv = (ysh[k][0][d] + ysh[k][1][d]) + (ysh[k][2][d] + ysh[k][3][d]);
        double yy = (double)yv * (double)yv;
        for (int off = 32; off; off >>= 1) yy += __shfl_down(yy, off, 64);
        if ((t & 63) == 0) scal[k] = yy;
    }
    __syncthreads();

    if (t == 0) {
        double S = 0.0, C0 = 0.0;
#pragma unroll
        for (int w = 0; w < 16; ++w) { S += redS[w]; C0 += redC[w]; }
#pragma unroll
        for (int k = 0; k < KPB; ++k) {
            const int p = pg * KPB + k;
            if (p < NPERM) {
                double T2 = 0.0, T3 = 0.0, T4 = 0.0;
#pragma unroll
                for (int w = 0; w < 16; ++w) {
                    T2 += red[w][k];
                    T3 += red[w][4 + k];
                    T4 += red[w][8 + k];
                }
                const double SV  = 0.5 * (C0 + T2 - 2.0 * T3 - 2.0 * T4);
                const double SV2 = (double)NN * S - scal[k];
                out[p] = (float)((SV2 - SV * SV / NPAIRF) / (NPAIRF - 1.0));
            }
        }
    }
}

extern "C" void kernel_launch(void* const* d_in, const int* in_sizes, int n_in,
                              void* d_out, int out_size, void* d_ws, size_t ws_size,
                              hipStream_t stream) {
    const float* data  = (const float*)d_in[0];
    const float* fermp = (const float*)d_in[1];
    const float* bosp  = (const float*)d_in[2];
    const int*   types = (const int*)d_in[3];
    const int*   perms = (const int*)d_in[4];
    float* out = (float*)d_out;

    double* srow = (double*)d_ws;                       // 320 f64
    double* rsda = (double*)((char*)d_ws + 4096);       // 320 f64
    float2* DAH  = (float2*)((char*)d_ws + 1048576);    // 320*320 float2 = 800 KB

    dah_kernel<<<NN, NN, 0, stream>>>(data, DAH, srow, rsda);
    qf_kernel<<<NBLK, 1024, 0, stream>>>(data, types, perms, fermp, bosp,
                                         (const float*)DAH, srow, rsda, out);
}